// Round 7
// baseline (343.589 us; speedup 1.0000x reference)
//
#include <hip/hip_runtime.h>

#define INV_T 14.285714285714286f  // 1/0.07
#define C1 0.055803571428571425f   // INV_T / 256 (undoes the 16x-per-input fp8 scale)

typedef float f32x16 __attribute__((ext_vector_type(16)));
typedef float f32x4 __attribute__((ext_vector_type(4)));
typedef int i32x4v __attribute__((ext_vector_type(4)));
typedef int i32x8 __attribute__((ext_vector_type(8)));

__device__ __forceinline__ unsigned char f2e4m3(float f) {
    unsigned char s = (unsigned char)((__float_as_uint(f) >> 24) & 0x80);
    float a = fabsf(f);
    if (a > 448.f) a = 448.f;
    if (a == 0.f) return s;
    int e = (int)((__float_as_uint(a) >> 23) & 0xFF) - 127;
    if (e < -10) return s;
    if (e < -6) e = -6;
    float scale = __int_as_float((unsigned)(130 - e) << 23);  // 2^(3-e)
    int mi = (int)rintf(a * scale);
    if (mi >= 16) { mi >>= 1; ++e; }
    if (mi < 8) return s | (unsigned char)mi;                  // subnormal (e==-6)
    return s | (unsigned char)(((e + 7) << 3) | (mi - 8));
}

__device__ __forceinline__ void async16(void* l, const void* g) {
    __builtin_amdgcn_global_load_lds(
        (const __attribute__((address_space(1))) unsigned int*)g,
        (__attribute__((address_space(3))) unsigned int*)l, 16, 0, 0);
}

// ---- merged: fp32->fp8(x16) convert + per-row distance/Sp/counts ----
__global__ void __launch_bounds__(256) k_prep(const float* __restrict__ emb,
                                              const float* __restrict__ center,
                                              const int* __restrict__ labels,
                                              unsigned char* __restrict__ embQ,
                                              float* __restrict__ out,
                                              float* __restrict__ Sp,
                                              int* __restrict__ cnt, int D) {
    int i = blockIdx.x;
    int tid = threadIdx.x;
    const float4* row = (const float4*)(emb + (size_t)i * D);
    const float4* c4 = (const float4*)center;
    float4 e = row[tid];
    float4 c = c4[tid];
    if (embQ)
        ((uchar4*)(embQ + (size_t)i * D))[tid] =
            make_uchar4(f2e4m3(e.x * 16.f), f2e4m3(e.y * 16.f),
                        f2e4m3(e.z * 16.f), f2e4m3(e.w * 16.f));
    float dx = e.x - c.x, dy = e.y - c.y, dz = e.z - c.z, dw = e.w - c.w;
    float d2 = dx * dx + dy * dy + dz * dz + dw * dw;
    float sp = e.x * c.x + e.y * c.y + e.z * c.z + e.w * c.w;
#pragma unroll
    for (int m = 1; m <= 32; m <<= 1) {
        d2 += __shfl_xor(d2, m, 64);
        sp += __shfl_xor(sp, m, 64);
    }
    __shared__ float sd2[4], ssp[4];
    int wave = tid >> 6;
    if ((tid & 63) == 0) { sd2[wave] = d2; ssp[wave] = sp; }
    __syncthreads();
    if (tid == 0) {
        float dd = sd2[0] + sd2[1] + sd2[2] + sd2[3];
        float ss = ssp[0] + ssp[1] + ssp[2] + ssp[3];
        out[5 + i] = sqrtf(dd);
        Sp[i] = ss * INV_T;
        atomicAdd(&cnt[labels[i] == 0 ? 0 : 1], 1);
    }
}

// ---- s_m[d] = sum over machine rows of emb[:,d] ----
__global__ void __launch_bounds__(256) k_colsum(const float* __restrict__ emb,
                                                const int* __restrict__ labels,
                                                float* __restrict__ s_m, int D) {
    int t = threadIdx.x;
    int r0 = blockIdx.x * 32;
    float4 acc = {0.f, 0.f, 0.f, 0.f};
#pragma unroll 4
    for (int r = 0; r < 32; ++r) {
        float sc = (labels[r0 + r] == 0) ? 1.f : 0.f;
        float4 v = ((const float4*)(emb + (size_t)(r0 + r) * D))[t];
        acc.x += v.x * sc; acc.y += v.y * sc; acc.z += v.z * sc; acc.w += v.w * sc;
    }
    atomicAdd(&s_m[t * 4 + 0], acc.x);
    atomicAdd(&s_m[t * 4 + 1], acc.y);
    atomicAdd(&s_m[t * 4 + 2], acc.z);
    atomicAdd(&s_m[t * 4 + 3], acc.w);
}

// ---- sumexp, barrier-free K-loop ----
// Block = 256 rows x 64 cols; rect-triangle cover (C >= 4R), strict grow<gcol
// mask. B-tile (64 cols, full K=1024) staged ONCE into 64 KB LDS (swizzled),
// then ONE barrier; each of the 4 waves (64 rows x 64 cols, 2x2 frags of
// mfma_scale 32x32x64 fp8) runs its whole K-loop with zero barriers:
// A streamed from L2 into registers (2-deep pipeline), B via conflict-free
// ds_read_b128. Epilogue: direct atomics, no LDS reduction.
#define MXMFMA(a, b, c) __builtin_amdgcn_mfma_scale_f32_32x32x64_f8f6f4( \
    (a), (b), (c), 0, 0, 0, 0x7F7F7F7F, 0, 0x7F7F7F7F)

__global__ void __launch_bounds__(256)
k_sumexp_nb(const unsigned char* __restrict__ embQ, float* __restrict__ sumexp,
            int D, int nRowT, int nColT) {
    // decode bid -> (R, C): off(R) = nColT*R - 2R^2 + 2R ; C = 4R + (bid - off)
    int bid = blockIdx.x;
    float bq = (float)(nColT + 2);
    int R = (int)((bq - sqrtf(fmaxf(bq * bq - 8.0f * (float)bid, 0.f))) * 0.25f);
    if (R < 0) R = 0;
    if (R > nRowT - 1) R = nRowT - 1;
#define OFF(r) (nColT * (r) - 2 * (r) * (r) + 2 * (r))
    while (R + 1 <= nRowT - 1 && OFF(R + 1) <= bid) ++R;
    while (R > 0 && OFF(R) > bid) --R;
    int C = 4 * R + (bid - OFF(R));
#undef OFF
    int rowbase = R * 256, colbase = C * 64;

    int tid = threadIdx.x;
    int wave = tid >> 6, lane = tid & 63;
    int l31 = lane & 31, kk = lane >> 5;

    __shared__ unsigned char sB[65536];  // 64 rows x 1024 B, 16B-chunk swizzled

    // ---- stage B once: 4096 chunks, 16 per thread ----
#pragma unroll
    for (int q = 0; q < 16; ++q) {
        int ch = q * 256 + tid;
        int row = ch >> 6, pcc = ch & 63;
        int gc = (pcc & 56) | ((pcc ^ row) & 7);  // inverse swizzle on global side
        async16(&sB[ch << 4], embQ + (size_t)(colbase + row) * D + gc * 16);
    }
    __syncthreads();  // drains vmcnt; the ONLY barrier

    f32x16 acc[2][2];
#pragma unroll
    for (int fr = 0; fr < 2; ++fr)
#pragma unroll
        for (int fc = 0; fc < 2; ++fc)
#pragma unroll
            for (int v = 0; v < 16; ++v) acc[fr][fc][v] = 0.f;

    // A row pointers: frag rows wave*64 + fr*32 + l31, lane owns K-bytes kk*32..+32
    const unsigned char* pa0 = embQ + (size_t)(rowbase + wave * 64 + l31) * D + kk * 32;
    const unsigned char* pa1 = pa0 + (size_t)32 * D;

#define LOADA(g, a0, a1)                                                  \
    do {                                                                  \
        i32x4v lo0 = *(const i32x4v*)(pa0 + (g) * 64);                    \
        i32x4v hi0 = *(const i32x4v*)(pa0 + (g) * 64 + 16);               \
        i32x4v lo1 = *(const i32x4v*)(pa1 + (g) * 64);                    \
        i32x4v hi1 = *(const i32x4v*)(pa1 + (g) * 64 + 16);               \
        a0 = __builtin_shufflevector(lo0, hi0, 0, 1, 2, 3, 4, 5, 6, 7);   \
        a1 = __builtin_shufflevector(lo1, hi1, 0, 1, 2, 3, 4, 5, 6, 7);   \
    } while (0)

    // B frag read: row r = fc*32+l31, chunks lc = g*4 + kk*2 + {0,1}, swizzled
#define LOADB(g, b0, b1)                                                  \
    do {                                                                  \
        int lc0 = (g) * 4 + kk * 2, lc1 = lc0 + 1;                        \
        int r0 = l31, r1 = 32 + l31;                                      \
        int p00 = (lc0 & 56) | ((lc0 ^ r0) & 7);                          \
        int p01 = (lc1 & 56) | ((lc1 ^ r0) & 7);                          \
        int p10 = (lc0 & 56) | ((lc0 ^ r1) & 7);                          \
        int p11 = (lc1 & 56) | ((lc1 ^ r1) & 7);                          \
        i32x4v lo0 = *(const i32x4v*)&sB[((r0 << 6) | p00) << 4];         \
        i32x4v hi0 = *(const i32x4v*)&sB[((r0 << 6) | p01) << 4];         \
        i32x4v lo1 = *(const i32x4v*)&sB[((r1 << 6) | p10) << 4];         \
        i32x4v hi1 = *(const i32x4v*)&sB[((r1 << 6) | p11) << 4];         \
        b0 = __builtin_shufflevector(lo0, hi0, 0, 1, 2, 3, 4, 5, 6, 7);   \
        b1 = __builtin_shufflevector(lo1, hi1, 0, 1, 2, 3, 4, 5, 6, 7);   \
    } while (0)

#define COMP(a0, a1, b0, b1)                       \
    do {                                           \
        acc[0][0] = MXMFMA(a0, b0, acc[0][0]);     \
        acc[0][1] = MXMFMA(a0, b1, acc[0][1]);     \
        acc[1][0] = MXMFMA(a1, b0, acc[1][0]);     \
        acc[1][1] = MXMFMA(a1, b1, acc[1][1]);     \
    } while (0)

    const int kG = D >> 6;  // K-64 groups (16)
    i32x8 Xa0, Xa1, Ya0, Ya1, Xb0, Xb1, Yb0, Yb1;
    LOADA(0, Xa0, Xa1);
    LOADB(0, Xb0, Xb1);
    for (int g = 0; g < kG; g += 2) {
        if (g + 1 < kG) {
            LOADA(g + 1, Ya0, Ya1);
            LOADB(g + 1, Yb0, Yb1);
        }
        COMP(Xa0, Xa1, Xb0, Xb1);
        if (g + 2 < kG) {
            LOADA(g + 2, Xa0, Xa1);
            LOADB(g + 2, Xb0, Xb1);
        }
        if (g + 1 < kG) COMP(Ya0, Ya1, Yb0, Yb1);
    }

    // ---- epilogue: exp over strictly-upper, direct atomics ----
    float rs[2][16];
    float cs[2] = {0.f, 0.f};
#pragma unroll
    for (int fr = 0; fr < 2; ++fr)
#pragma unroll
        for (int v = 0; v < 16; ++v) rs[fr][v] = 0.f;

#pragma unroll
    for (int fr = 0; fr < 2; ++fr)
#pragma unroll
        for (int fc = 0; fc < 2; ++fc) {
            int gcol = colbase + fc * 32 + l31;
#pragma unroll
            for (int v = 0; v < 16; ++v) {
                int grow = rowbase + wave * 64 + fr * 32 + (v & 3) + 8 * (v >> 2) + 4 * kk;
                float e = (grow < gcol) ? __expf(acc[fr][fc][v] * C1 - INV_T) : 0.f;
                rs[fr][v] += e;
                cs[fc] += e;
            }
        }

    // row sums: reduce over the 32 col-lanes (bits 0..4); each surviving lane
    // (l31==0, kk = 0/1) holds 32 distinct rows
#pragma unroll
    for (int m = 1; m <= 16; m <<= 1)
#pragma unroll
        for (int fr = 0; fr < 2; ++fr)
#pragma unroll
            for (int v = 0; v < 16; ++v) rs[fr][v] += __shfl_xor(rs[fr][v], m, 64);
    if (l31 == 0) {
#pragma unroll
        for (int fr = 0; fr < 2; ++fr)
#pragma unroll
            for (int v = 0; v < 16; ++v) {
                int grow = rowbase + wave * 64 + fr * 32 + (v & 3) + 8 * (v >> 2) + 4 * kk;
                atomicAdd(&sumexp[grow], rs[fr][v]);
            }
    }
    // col sums: reduce over the two kk halves (bit 5)
#pragma unroll
    for (int fc = 0; fc < 2; ++fc) cs[fc] += __shfl_xor(cs[fc], 32, 64);
    if (kk == 0) {
#pragma unroll
        for (int fc = 0; fc < 2; ++fc)
            atomicAdd(&sumexp[colbase + fc * 32 + l31], cs[fc]);
    }
}

// ---- fallback (no workspace): bf16-via-LDS, fp32 inline convert ----
typedef __bf16 bf16x8 __attribute__((ext_vector_type(8)));
typedef unsigned short u16x8 __attribute__((ext_vector_type(8)));
__device__ __forceinline__ unsigned short f2bf(float f) {
    unsigned int x = __float_as_uint(f);
    x += 0x7fffu + ((x >> 16) & 1u);
    return (unsigned short)(x >> 16);
}
__global__ void __launch_bounds__(256) k_sumexp_fb(const float* __restrict__ embF,
                                                   float* __restrict__ sumexp, int D, int nTiles) {
    int bid = blockIdx.x;
    const int n = nTiles;
    float nf = (float)n + 0.5f;
    int rb = (int)(nf - sqrtf(fmaxf(nf * nf - 2.0f * (float)bid, 0.f)));
    if (rb < 0) rb = 0;
    if (rb > n - 1) rb = n - 1;
#define TRI_OFF(r) ((r) * n - ((r) * ((r)-1)) / 2)
    while (rb + 1 <= n - 1 && TRI_OFF(rb + 1) <= bid) ++rb;
    while (rb > 0 && TRI_OFF(rb) > bid) --rb;
    int cb = rb + (bid - TRI_OFF(rb));
#undef TRI_OFF
    int tid = threadIdx.x;
    int wave = tid >> 6, lane = tid & 63;
    int wr = wave >> 1, wc = wave & 1;
    int quad = lane >> 4, l15 = lane & 15;
    int rowbase = rb * 128, colbase = cb * 128;
    __shared__ unsigned short lA[128 * 64];
    __shared__ unsigned short lB[128 * 64];
    __shared__ float rred[2][128];
    __shared__ float cred[2][128];
    f32x4 zero = {0.f, 0.f, 0.f, 0.f};
    f32x4 acc[4][4];
#pragma unroll
    for (int r = 0; r < 4; ++r)
#pragma unroll
        for (int c = 0; c < 4; ++c) acc[r][c] = zero;
    const int kIters = D >> 6;
    for (int kt = 0; kt < kIters; ++kt) {
        int k0 = kt << 6;
#pragma unroll
        for (int q = 0; q < 4; ++q) {
            int ch = q * 256 + tid;
            int row = ch >> 3, lc = ch & 7;
            int pc = lc ^ (row & 7);
            const float4* sa = (const float4*)(embF + (size_t)(rowbase + row) * D + k0 + lc * 8);
            const float4* sb = (const float4*)(embF + (size_t)(colbase + row) * D + k0 + lc * 8);
            float4 a0 = sa[0], a1 = sa[1];
            float4 b0 = sb[0], b1 = sb[1];
            u16x8 va = {f2bf(a0.x), f2bf(a0.y), f2bf(a0.z), f2bf(a0.w),
                        f2bf(a1.x), f2bf(a1.y), f2bf(a1.z), f2bf(a1.w)};
            u16x8 vb = {f2bf(b0.x), f2bf(b0.y), f2bf(b0.z), f2bf(b0.w),
                        f2bf(b1.x), f2bf(b1.y), f2bf(b1.z), f2bf(b1.w)};
            *(u16x8*)&lA[(row << 6) + (pc << 3)] = va;
            *(u16x8*)&lB[(row << 6) + (pc << 3)] = vb;
        }
        __syncthreads();
#pragma unroll
        for (int h = 0; h < 2; ++h) {
            bf16x8 af[4], bfr[4];
#pragma unroll
            for (int r = 0; r < 4; ++r) {
                int row = wr * 64 + r * 16 + l15;
                int pc = (h * 4 + quad) ^ (l15 & 7);
                af[r] = *(const bf16x8*)&lA[(row << 6) + (pc << 3)];
            }
#pragma unroll
            for (int c = 0; c < 4; ++c) {
                int row = wc * 64 + c * 16 + l15;
                int pc = (h * 4 + quad) ^ (l15 & 7);
                bfr[c] = *(const bf16x8*)&lB[(row << 6) + (pc << 3)];
            }
#pragma unroll
            for (int r = 0; r < 4; ++r)
#pragma unroll
                for (int c = 0; c < 4; ++c)
                    acc[r][c] = __builtin_amdgcn_mfma_f32_16x16x32_bf16(af[r], bfr[c], acc[r][c], 0, 0, 0);
        }
        __syncthreads();
    }
    float rs[4][4], cs[4];
#pragma unroll
    for (int r = 0; r < 4; ++r)
#pragma unroll
        for (int v = 0; v < 4; ++v) rs[r][v] = 0.f;
#pragma unroll
    for (int c = 0; c < 4; ++c) cs[c] = 0.f;
#pragma unroll
    for (int r = 0; r < 4; ++r)
#pragma unroll
        for (int c = 0; c < 4; ++c) {
            f32x4 a = acc[r][c];
            int gcol = colbase + wc * 64 + c * 16 + l15;
#pragma unroll
            for (int v = 0; v < 4; ++v) {
                int grow = rowbase + wr * 64 + r * 16 + quad * 4 + v;
                float e = (grow < gcol) ? __expf((a[v] - 1.0f) * INV_T) : 0.f;
                rs[r][v] += e;
                cs[c] += e;
            }
        }
#pragma unroll
    for (int m = 1; m <= 8; m <<= 1)
#pragma unroll
        for (int r = 0; r < 4; ++r)
#pragma unroll
            for (int v = 0; v < 4; ++v) rs[r][v] += __shfl_xor(rs[r][v], m, 64);
    if (l15 == 0)
#pragma unroll
        for (int r = 0; r < 4; ++r)
#pragma unroll
            for (int v = 0; v < 4; ++v)
                rred[wc][wr * 64 + r * 16 + quad * 4 + v] = rs[r][v];
#pragma unroll
    for (int m = 16; m <= 32; m <<= 1)
#pragma unroll
        for (int c = 0; c < 4; ++c) cs[c] += __shfl_xor(cs[c], m, 64);
    if (quad == 0)
#pragma unroll
        for (int c = 0; c < 4; ++c) cred[wr][wc * 64 + c * 16 + l15] = cs[c];
    __syncthreads();
    if (tid < 128) {
        atomicAdd(&sumexp[rowbase + tid], rred[0][tid] + rred[1][tid]);
    } else {
        int u = tid & 127;
        atomicAdd(&sumexp[colbase + u], cred[0][u] + cred[1][u]);
    }
}

// ---- per-row finalize ----
__global__ void __launch_bounds__(256) k_finalize(const float* __restrict__ emb,
                                                  const float* __restrict__ s_m,
                                                  const float* __restrict__ Sp,
                                                  const float* __restrict__ sumexp,
                                                  const int* __restrict__ labels,
                                                  const float* __restrict__ outv,
                                                  const float* __restrict__ rmp,
                                                  const float* __restrict__ rhp,
                                                  float* __restrict__ scal, int D) {
    int tid = threadIdx.x;
    int wave = tid >> 6, lane = tid & 63;
    __shared__ float ac[8];
    if (tid < 8) ac[tid] = 0.f;
    __syncthreads();
    float rm = rmp[0], rh = rhp[0];
    const float4* sm4 = (const float4*)s_m;
    for (int it = 0; it < 8; ++it) {
        int i = blockIdx.x * 32 + it * 4 + wave;
        const float4* row = (const float4*)(emb + (size_t)i * D);
        float q = 0.f, sd = 0.f;
#pragma unroll
        for (int j = 0; j < 4; ++j) {
            float4 e = row[lane * 4 + j];
            float4 s = sm4[lane * 4 + j];
            q += e.x * s.x + e.y * s.y + e.z * s.z + e.w * s.w;
            sd += e.x * e.x + e.y * e.y + e.z * e.z + e.w * e.w;
        }
#pragma unroll
        for (int m = 1; m <= 32; m <<= 1) {
            q += __shfl_xor(q, m, 64);
            sd += __shfl_xor(sd, m, 64);
        }
        if (lane == 0) {
            float LP = Sp[i];
            float eS = __expf(LP - INV_T);
            float lse = INV_T + __logf(sumexp[i] + eS);
            bool mach = (labels[i] == 0);
            float pos = (q - (mach ? sd : 0.f)) * INV_T + LP;
            float d = outv[5 + i];
            atomicAdd(&ac[2], eS);
            if (mach) {
                atomicAdd(&ac[4], lse);
                atomicAdd(&ac[5], pos);
                atomicAdd(&ac[3], LP);
                float x = d - rm;
                if (x > 0.f) atomicAdd(&ac[0], x * x);
            } else {
                float x = rh - d;
                if (x > 0.f) atomicAdd(&ac[1], x * x);
            }
        }
    }
    __syncthreads();
    if (tid < 8) atomicAdd(&scal[tid], ac[tid]);
}

// ---- combine scalars ----
__global__ void k_final(const float* __restrict__ scal, const int* __restrict__ cnt,
                        float* __restrict__ out) {
    if (threadIdx.x == 0) {
        int nm = cnt[0], nh = cnt[1];
        float nmf = (float)(nm > 1 ? nm : 1);
        float nhf = (float)(nh > 1 ? nh : 1);
        float loss_m = scal[0] / nmf;
        float loss_h = scal[1] / nhf;
        float loss_shell = loss_m + loss_h;
        float lse_p = INV_T + __logf(scal[2]);
        float proto = lse_p - scal[3] / nmf;
        float con = scal[4] - scal[5] / nmf;
        int denom = (nm + 1 > 1) ? nm + 1 : 1;
        float lc = (con + proto) / (float)denom;
        if (!(nm > 0 && nh > 0)) lc = 0.f;
        out[0] = loss_shell + lc;
        out[1] = loss_shell;
        out[2] = loss_m;
        out[3] = loss_h;
        out[4] = lc;
    }
}

extern "C" void kernel_launch(void* const* d_in, const int* in_sizes, int n_in,
                              void* d_out, int out_size, void* d_ws, size_t ws_size,
                              hipStream_t stream) {
    const float* emb = (const float*)d_in[0];
    const float* center = (const float*)d_in[1];
    const float* rmp = (const float*)d_in[2];
    const float* rhp = (const float*)d_in[3];
    const int* labels = (const int*)d_in[4];
    float* out = (float*)d_out;
    const int B = in_sizes[4];
    const int D = in_sizes[1];

    size_t qBytes = (size_t)B * D;  // fp8 copy
    size_t auxBytes = (size_t)B * 4 + (size_t)D * 4 + 256 + (size_t)B * 4;
    bool pre = ws_size >= qBytes + auxBytes;
    size_t Z0 = pre ? qBytes : 0;

    char* ws = (char*)d_ws;
    unsigned char* embQ = (unsigned char*)ws;
    float* sumexp = (float*)(ws + Z0);
    float* s_m = (float*)(ws + Z0 + (size_t)B * 4);
    float* scal = (float*)(ws + Z0 + (size_t)B * 4 + (size_t)D * 4);
    int* cnt = (int*)(scal + 8);
    float* Sp = (float*)(ws + Z0 + (size_t)B * 4 + (size_t)D * 4 + 256);

    hipMemsetAsync(ws + Z0, 0, (size_t)B * 4 + (size_t)D * 4 + 256, stream);

    k_prep<<<B, D / 4, 0, stream>>>(emb, center, labels, pre ? embQ : nullptr, out, Sp, cnt, D);
    k_colsum<<<B / 32, D / 4, 0, stream>>>(emb, labels, s_m, D);

    if (pre) {
        int nRowT = B / 256, nColT = B / 64;
        int nBlocks = nColT * nRowT - 2 * nRowT * nRowT + 2 * nRowT;  // 2112 @ B=8192
        k_sumexp_nb<<<nBlocks, 256, 0, stream>>>(embQ, sumexp, D, nRowT, nColT);
    } else {
        int nT = B / 128;
        int nBlocks = nT * (nT + 1) / 2;
        k_sumexp_fb<<<nBlocks, 256, 0, stream>>>(emb, sumexp, D, nT);
    }

    k_finalize<<<B / 32, 256, 0, stream>>>(emb, s_m, Sp, sumexp, labels, out, rmp, rhp, scal, D);
    k_final<<<1, 64, 0, stream>>>(scal, cnt, out);
}

// Round 8
// 283.002 us; speedup vs baseline: 1.2141x; 1.2141x over previous
//
#include <hip/hip_runtime.h>

#define INV_T 14.285714285714286f  // 1/0.07
#define C1 0.055803571428571425f   // INV_T / 256 (undoes the 16x-per-input fp8 scale)

typedef float f32x16 __attribute__((ext_vector_type(16)));
typedef float f32x4 __attribute__((ext_vector_type(4)));
typedef int i32x4v __attribute__((ext_vector_type(4)));
typedef int i32x8 __attribute__((ext_vector_type(8)));

__device__ __forceinline__ unsigned char f2e4m3(float f) {
    unsigned char s = (unsigned char)((__float_as_uint(f) >> 24) & 0x80);
    float a = fabsf(f);
    if (a > 448.f) a = 448.f;
    if (a == 0.f) return s;
    int e = (int)((__float_as_uint(a) >> 23) & 0xFF) - 127;
    if (e < -10) return s;
    if (e < -6) e = -6;
    float scale = __int_as_float((unsigned)(130 - e) << 23);  // 2^(3-e)
    int mi = (int)rintf(a * scale);
    if (mi >= 16) { mi >>= 1; ++e; }
    if (mi < 8) return s | (unsigned char)mi;                  // subnormal (e==-6)
    return s | (unsigned char)(((e + 7) << 3) | (mi - 8));
}

__device__ __forceinline__ void async16(void* l, const void* g) {
    __builtin_amdgcn_global_load_lds(
        (const __attribute__((address_space(1))) unsigned int*)g,
        (__attribute__((address_space(3))) unsigned int*)l, 16, 0, 0);
}

// ---- merged: fp32->fp8(x16) convert + per-row distance/Sp/counts ----
__global__ void __launch_bounds__(256) k_prep(const float* __restrict__ emb,
                                              const float* __restrict__ center,
                                              const int* __restrict__ labels,
                                              unsigned char* __restrict__ embQ,
                                              float* __restrict__ out,
                                              float* __restrict__ Sp,
                                              int* __restrict__ cnt, int D) {
    int i = blockIdx.x;
    int tid = threadIdx.x;
    const float4* row = (const float4*)(emb + (size_t)i * D);
    const float4* c4 = (const float4*)center;
    float4 e = row[tid];
    float4 c = c4[tid];
    if (embQ)
        ((uchar4*)(embQ + (size_t)i * D))[tid] =
            make_uchar4(f2e4m3(e.x * 16.f), f2e4m3(e.y * 16.f),
                        f2e4m3(e.z * 16.f), f2e4m3(e.w * 16.f));
    float dx = e.x - c.x, dy = e.y - c.y, dz = e.z - c.z, dw = e.w - c.w;
    float d2 = dx * dx + dy * dy + dz * dz + dw * dw;
    float sp = e.x * c.x + e.y * c.y + e.z * c.z + e.w * c.w;
#pragma unroll
    for (int m = 1; m <= 32; m <<= 1) {
        d2 += __shfl_xor(d2, m, 64);
        sp += __shfl_xor(sp, m, 64);
    }
    __shared__ float sd2[4], ssp[4];
    int wave = tid >> 6;
    if ((tid & 63) == 0) { sd2[wave] = d2; ssp[wave] = sp; }
    __syncthreads();
    if (tid == 0) {
        float dd = sd2[0] + sd2[1] + sd2[2] + sd2[3];
        float ss = ssp[0] + ssp[1] + ssp[2] + ssp[3];
        out[5 + i] = sqrtf(dd);
        Sp[i] = ss * INV_T;
        atomicAdd(&cnt[labels[i] == 0 ? 0 : 1], 1);
    }
}

// ---- s_m[d] = sum over machine rows of emb[:,d] ----
__global__ void __launch_bounds__(256) k_colsum(const float* __restrict__ emb,
                                                const int* __restrict__ labels,
                                                float* __restrict__ s_m, int D) {
    int t = threadIdx.x;
    int r0 = blockIdx.x * 32;
    float4 acc = {0.f, 0.f, 0.f, 0.f};
#pragma unroll 4
    for (int r = 0; r < 32; ++r) {
        float sc = (labels[r0 + r] == 0) ? 1.f : 0.f;
        float4 v = ((const float4*)(emb + (size_t)(r0 + r) * D))[t];
        acc.x += v.x * sc; acc.y += v.y * sc; acc.z += v.z * sc; acc.w += v.w * sc;
    }
    atomicAdd(&s_m[t * 4 + 0], acc.x);
    atomicAdd(&s_m[t * 4 + 1], acc.y);
    atomicAdd(&s_m[t * 4 + 2], acc.z);
    atomicAdd(&s_m[t * 4 + 3], acc.w);
}

// ---- sumexp via MX fp8 MFMA; R6 structure with 16-segment DMA staging ----
// 128x128 tiles over triangle; 4 waves of 64x64 (2x2 frags of
// mfma_scale 32x32x64). LDS row-major 16B chunks, XOR-swizzled on the
// GLOBAL side: phys slot (row, lc) holds global chunk lc^(row&7). Lane
// octets of each DMA instruction cover one 128B row-span (permuted) ->
// 16 segments/instr (vs 64 in R6's c-major layout). Fragment reads:
// chunk c of row r at phys c^(r&7); bank family measured 0-conflict (R2/R4).
#define MXMFMA(a, b, c) __builtin_amdgcn_mfma_scale_f32_32x32x64_f8f6f4( \
    (a), (b), (c), 0, 0, 0, 0x7F7F7F7F, 0, 0x7F7F7F7F)

__global__ void __launch_bounds__(256, 2)
k_sumexp_mx(const unsigned char* __restrict__ embQ, float* __restrict__ sumexp,
            int D, int nT) {
    int bid = blockIdx.x;
    const int n = nT;
    float nf = (float)n + 0.5f;
    int rb = (int)(nf - sqrtf(fmaxf(nf * nf - 2.0f * (float)bid, 0.f)));
    if (rb < 0) rb = 0;
    if (rb > n - 1) rb = n - 1;
#define TRI_OFF(r) ((r) * n - ((r) * ((r)-1)) / 2)
    while (rb + 1 <= n - 1 && TRI_OFF(rb + 1) <= bid) ++rb;
    while (rb > 0 && TRI_OFF(rb) > bid) --rb;
    int cb = rb + (bid - TRI_OFF(rb));
#undef TRI_OFF
    int rowbase = rb * 128, colbase = cb * 128;

    int tid = threadIdx.x;
    int wave = tid >> 6, lane = tid & 63;
    int wr = wave >> 1, wc = wave & 1;
    int l31 = lane & 31, kk = lane >> 5;

    __shared__ unsigned char sA[2][16384];  // 128 rows x 8 chunks of 16B (K=128)
    __shared__ unsigned char sB[2][16384];
    __shared__ float rred[2][128];
    __shared__ float cred[2][128];

    f32x16 acc[2][2];
#pragma unroll
    for (int fr = 0; fr < 2; ++fr)
#pragma unroll
        for (int fc = 0; fc < 2; ++fc)
#pragma unroll
            for (int v = 0; v < 16; ++v) acc[fr][fc][v] = 0.f;

    const int kG = D >> 7;  // K-tiles of 128 (8)

    // staging: 1024 chunks each for A and B; thread handles 4+4.
    // dest slot = ch (row-major); source chunk = (ch&7) ^ (row&7).
    const unsigned char* gSA[4];
    const unsigned char* gSB[4];
    unsigned int dstOff[4];
#pragma unroll
    for (int q = 0; q < 4; ++q) {
        int ch = q * 256 + tid;
        int row = ch >> 3, lc = ch & 7;
        int gc = lc ^ (row & 7);
        gSA[q] = embQ + (size_t)(rowbase + row) * D + gc * 16;
        gSB[q] = embQ + (size_t)(colbase + row) * D + gc * 16;
        dstOff[q] = (unsigned)ch << 4;
    }

    auto stage = [&](int buf, int kt) {
        int ko = kt << 7;
#pragma unroll
        for (int q = 0; q < 4; ++q) {
            async16(&sA[buf][dstOff[q]], gSA[q] + ko);
            async16(&sB[buf][dstOff[q]], gSB[q] + ko);
        }
    };

    // fragment-read lane constants: row e = l31&7 for ALL frag rows
    // (row = base + {0,32}+l31; 32,64-multiples drop out of &7)
    int e7 = (l31 & 7) << 4;
    int offs[2][2];
#pragma unroll
    for (int h = 0; h < 2; ++h)
#pragma unroll
        for (int j = 0; j < 2; ++j)
            offs[h][j] = (((h * 4 + kk * 2 + j) << 4) ^ e7);
    int aBase0 = (wr * 64 + l31) << 7;   // *128 B/row
    int aBase1 = aBase0 + (32 << 7);
    int bBase0 = (wc * 64 + l31) << 7;
    int bBase1 = bBase0 + (32 << 7);

    stage(0, 0);
    for (int kt = 0; kt < kG; ++kt) {
        int cur = kt & 1;
        __syncthreads();                          // cur DMA landed, prev reads done
        if (kt + 1 < kG) stage(cur ^ 1, kt + 1);  // prefetch in flight during compute
        const unsigned char* A = sA[cur];
        const unsigned char* Bp = sB[cur];
#pragma unroll
        for (int h = 0; h < 2; ++h) {             // two K-64 halves
            i32x8 av[2], bv[2];
            {
                i32x4v lo = *(const i32x4v*)&A[aBase0 + offs[h][0]];
                i32x4v hi = *(const i32x4v*)&A[aBase0 + offs[h][1]];
                av[0] = __builtin_shufflevector(lo, hi, 0, 1, 2, 3, 4, 5, 6, 7);
            }
            {
                i32x4v lo = *(const i32x4v*)&A[aBase1 + offs[h][0]];
                i32x4v hi = *(const i32x4v*)&A[aBase1 + offs[h][1]];
                av[1] = __builtin_shufflevector(lo, hi, 0, 1, 2, 3, 4, 5, 6, 7);
            }
            {
                i32x4v lo = *(const i32x4v*)&Bp[bBase0 + offs[h][0]];
                i32x4v hi = *(const i32x4v*)&Bp[bBase0 + offs[h][1]];
                bv[0] = __builtin_shufflevector(lo, hi, 0, 1, 2, 3, 4, 5, 6, 7);
            }
            {
                i32x4v lo = *(const i32x4v*)&Bp[bBase1 + offs[h][0]];
                i32x4v hi = *(const i32x4v*)&Bp[bBase1 + offs[h][1]];
                bv[1] = __builtin_shufflevector(lo, hi, 0, 1, 2, 3, 4, 5, 6, 7);
            }
#pragma unroll
            for (int fr = 0; fr < 2; ++fr)
#pragma unroll
                for (int fc = 0; fc < 2; ++fc)
                    acc[fr][fc] = MXMFMA(av[fr], bv[fc], acc[fr][fc]);
        }
    }

    // epilogue: exp over strictly-upper elements + row/col reductions
    float rs[2][16];
    float cs[2] = {0.f, 0.f};
#pragma unroll
    for (int fr = 0; fr < 2; ++fr)
#pragma unroll
        for (int v = 0; v < 16; ++v) rs[fr][v] = 0.f;

#pragma unroll
    for (int fr = 0; fr < 2; ++fr)
#pragma unroll
        for (int fc = 0; fc < 2; ++fc) {
            int gcol = colbase + wc * 64 + fc * 32 + l31;
#pragma unroll
            for (int v = 0; v < 16; ++v) {
                int grow = rowbase + wr * 64 + fr * 32 + (v & 3) + 8 * (v >> 2) + 4 * kk;
                float e = (grow < gcol) ? __expf(acc[fr][fc][v] * C1 - INV_T) : 0.f;
                rs[fr][v] += e;
                cs[fc] += e;
            }
        }

#pragma unroll
    for (int m = 1; m <= 16; m <<= 1)
#pragma unroll
        for (int fr = 0; fr < 2; ++fr)
#pragma unroll
            for (int v = 0; v < 16; ++v) rs[fr][v] += __shfl_xor(rs[fr][v], m, 64);
    if (l31 == 0)
#pragma unroll
        for (int fr = 0; fr < 2; ++fr)
#pragma unroll
            for (int v = 0; v < 16; ++v)
                rred[wc][wr * 64 + fr * 32 + (v & 3) + 8 * (v >> 2) + 4 * kk] = rs[fr][v];

#pragma unroll
    for (int fc = 0; fc < 2; ++fc) cs[fc] += __shfl_xor(cs[fc], 32, 64);
    if (kk == 0)
#pragma unroll
        for (int fc = 0; fc < 2; ++fc) cred[wr][wc * 64 + fc * 32 + l31] = cs[fc];

    __syncthreads();
    if (tid < 128) {
        atomicAdd(&sumexp[rowbase + tid], rred[0][tid] + rred[1][tid]);
    } else {
        int u = tid - 128;
        atomicAdd(&sumexp[colbase + u], cred[0][u] + cred[1][u]);
    }
}

// ---- fallback (no workspace): bf16-via-LDS, fp32 inline convert ----
typedef __bf16 bf16x8 __attribute__((ext_vector_type(8)));
typedef unsigned short u16x8 __attribute__((ext_vector_type(8)));
__device__ __forceinline__ unsigned short f2bf(float f) {
    unsigned int x = __float_as_uint(f);
    x += 0x7fffu + ((x >> 16) & 1u);
    return (unsigned short)(x >> 16);
}
__global__ void __launch_bounds__(256) k_sumexp_fb(const float* __restrict__ embF,
                                                   float* __restrict__ sumexp, int D, int nTiles) {
    int bid = blockIdx.x;
    const int n = nTiles;
    float nf = (float)n + 0.5f;
    int rb = (int)(nf - sqrtf(fmaxf(nf * nf - 2.0f * (float)bid, 0.f)));
    if (rb < 0) rb = 0;
    if (rb > n - 1) rb = n - 1;
#define TRI_OFF(r) ((r) * n - ((r) * ((r)-1)) / 2)
    while (rb + 1 <= n - 1 && TRI_OFF(rb + 1) <= bid) ++rb;
    while (rb > 0 && TRI_OFF(rb) > bid) --rb;
    int cb = rb + (bid - TRI_OFF(rb));
#undef TRI_OFF
    int tid = threadIdx.x;
    int wave = tid >> 6, lane = tid & 63;
    int wr = wave >> 1, wc = wave & 1;
    int quad = lane >> 4, l15 = lane & 15;
    int rowbase = rb * 128, colbase = cb * 128;
    __shared__ unsigned short lA[128 * 64];
    __shared__ unsigned short lB[128 * 64];
    __shared__ float rred[2][128];
    __shared__ float cred[2][128];
    f32x4 zero = {0.f, 0.f, 0.f, 0.f};
    f32x4 acc[4][4];
#pragma unroll
    for (int r = 0; r < 4; ++r)
#pragma unroll
        for (int c = 0; c < 4; ++c) acc[r][c] = zero;
    const int kIters = D >> 6;
    for (int kt = 0; kt < kIters; ++kt) {
        int k0 = kt << 6;
#pragma unroll
        for (int q = 0; q < 4; ++q) {
            int ch = q * 256 + tid;
            int row = ch >> 3, lc = ch & 7;
            int pc = lc ^ (row & 7);
            const float4* sa = (const float4*)(embF + (size_t)(rowbase + row) * D + k0 + lc * 8);
            const float4* sb = (const float4*)(embF + (size_t)(colbase + row) * D + k0 + lc * 8);
            float4 a0 = sa[0], a1 = sa[1];
            float4 b0 = sb[0], b1 = sb[1];
            u16x8 va = {f2bf(a0.x), f2bf(a0.y), f2bf(a0.z), f2bf(a0.w),
                        f2bf(a1.x), f2bf(a1.y), f2bf(a1.z), f2bf(a1.w)};
            u16x8 vb = {f2bf(b0.x), f2bf(b0.y), f2bf(b0.z), f2bf(b0.w),
                        f2bf(b1.x), f2bf(b1.y), f2bf(b1.z), f2bf(b1.w)};
            *(u16x8*)&lA[(row << 6) + (pc << 3)] = va;
            *(u16x8*)&lB[(row << 6) + (pc << 3)] = vb;
        }
        __syncthreads();
#pragma unroll
        for (int h = 0; h < 2; ++h) {
            bf16x8 af[4], bfr[4];
#pragma unroll
            for (int r = 0; r < 4; ++r) {
                int row = wr * 64 + r * 16 + l15;
                int pc = (h * 4 + quad) ^ (l15 & 7);
                af[r] = *(const bf16x8*)&lA[(row << 6) + (pc << 3)];
            }
#pragma unroll
            for (int c = 0; c < 4; ++c) {
                int row = wc * 64 + c * 16 + l15;
                int pc = (h * 4 + quad) ^ (l15 & 7);
                bfr[c] = *(const bf16x8*)&lB[(row << 6) + (pc << 3)];
            }
#pragma unroll
            for (int r = 0; r < 4; ++r)
#pragma unroll
                for (int c = 0; c < 4; ++c)
                    acc[r][c] = __builtin_amdgcn_mfma_f32_16x16x32_bf16(af[r], bfr[c], acc[r][c], 0, 0, 0);
        }
        __syncthreads();
    }
    float rs[4][4], cs[4];
#pragma unroll
    for (int r = 0; r < 4; ++r)
#pragma unroll
        for (int v = 0; v < 4; ++v) rs[r][v] = 0.f;
#pragma unroll
    for (int c = 0; c < 4; ++c) cs[c] = 0.f;
#pragma unroll
    for (int r = 0; r < 4; ++r)
#pragma unroll
        for (int c = 0; c < 4; ++c) {
            f32x4 a = acc[r][c];
            int gcol = colbase + wc * 64 + c * 16 + l15;
#pragma unroll
            for (int v = 0; v < 4; ++v) {
                int grow = rowbase + wr * 64 + r * 16 + quad * 4 + v;
                float e = (grow < gcol) ? __expf((a[v] - 1.0f) * INV_T) : 0.f;
                rs[r][v] += e;
                cs[c] += e;
            }
        }
#pragma unroll
    for (int m = 1; m <= 8; m <<= 1)
#pragma unroll
        for (int r = 0; r < 4; ++r)
#pragma unroll
            for (int v = 0; v < 4; ++v) rs[r][v] += __shfl_xor(rs[r][v], m, 64);
    if (l15 == 0)
#pragma unroll
        for (int r = 0; r < 4; ++r)
#pragma unroll
            for (int v = 0; v < 4; ++v)
                rred[wc][wr * 64 + r * 16 + quad * 4 + v] = rs[r][v];
#pragma unroll
    for (int m = 16; m <= 32; m <<= 1)
#pragma unroll
        for (int c = 0; c < 4; ++c) cs[c] += __shfl_xor(cs[c], m, 64);
    if (quad == 0)
#pragma unroll
        for (int c = 0; c < 4; ++c) cred[wr][wc * 64 + c * 16 + l15] = cs[c];
    __syncthreads();
    if (tid < 128) {
        atomicAdd(&sumexp[rowbase + tid], rred[0][tid] + rred[1][tid]);
    } else {
        int u = tid & 127;
        atomicAdd(&sumexp[colbase + u], cred[0][u] + cred[1][u]);
    }
}

// ---- per-row finalize ----
__global__ void __launch_bounds__(256) k_finalize(const float* __restrict__ emb,
                                                  const float* __restrict__ s_m,
                                                  const float* __restrict__ Sp,
                                                  const float* __restrict__ sumexp,
                                                  const int* __restrict__ labels,
                                                  const float* __restrict__ outv,
                                                  const float* __restrict__ rmp,
                                                  const float* __restrict__ rhp,
                                                  float* __restrict__ scal, int D) {
    int tid = threadIdx.x;
    int wave = tid >> 6, lane = tid & 63;
    __shared__ float ac[8];
    if (tid < 8) ac[tid] = 0.f;
    __syncthreads();
    float rm = rmp[0], rh = rhp[0];
    const float4* sm4 = (const float4*)s_m;
    for (int it = 0; it < 8; ++it) {
        int i = blockIdx.x * 32 + it * 4 + wave;
        const float4* row = (const float4*)(emb + (size_t)i * D);
        float q = 0.f, sd = 0.f;
#pragma unroll
        for (int j = 0; j < 4; ++j) {
            float4 e = row[lane * 4 + j];
            float4 s = sm4[lane * 4 + j];
            q += e.x * s.x + e.y * s.y + e.z * s.z + e.w * s.w;
            sd += e.x * e.x + e.y * e.y + e.z * e.z + e.w * e.w;
        }
#pragma unroll
        for (int m = 1; m <= 32; m <<= 1) {
            q += __shfl_xor(q, m, 64);
            sd += __shfl_xor(sd, m, 64);
        }
        if (lane == 0) {
            float LP = Sp[i];
            float eS = __expf(LP - INV_T);
            float lse = INV_T + __logf(sumexp[i] + eS);
            bool mach = (labels[i] == 0);
            float pos = (q - (mach ? sd : 0.f)) * INV_T + LP;
            float d = outv[5 + i];
            atomicAdd(&ac[2], eS);
            if (mach) {
                atomicAdd(&ac[4], lse);
                atomicAdd(&ac[5], pos);
                atomicAdd(&ac[3], LP);
                float x = d - rm;
                if (x > 0.f) atomicAdd(&ac[0], x * x);
            } else {
                float x = rh - d;
                if (x > 0.f) atomicAdd(&ac[1], x * x);
            }
        }
    }
    __syncthreads();
    if (tid < 8) atomicAdd(&scal[tid], ac[tid]);
}

// ---- combine scalars ----
__global__ void k_final(const float* __restrict__ scal, const int* __restrict__ cnt,
                        float* __restrict__ out) {
    if (threadIdx.x == 0) {
        int nm = cnt[0], nh = cnt[1];
        float nmf = (float)(nm > 1 ? nm : 1);
        float nhf = (float)(nh > 1 ? nh : 1);
        float loss_m = scal[0] / nmf;
        float loss_h = scal[1] / nhf;
        float loss_shell = loss_m + loss_h;
        float lse_p = INV_T + __logf(scal[2]);
        float proto = lse_p - scal[3] / nmf;
        float con = scal[4] - scal[5] / nmf;
        int denom = (nm + 1 > 1) ? nm + 1 : 1;
        float lc = (con + proto) / (float)denom;
        if (!(nm > 0 && nh > 0)) lc = 0.f;
        out[0] = loss_shell + lc;
        out[1] = loss_shell;
        out[2] = loss_m;
        out[3] = loss_h;
        out[4] = lc;
    }
}

extern "C" void kernel_launch(void* const* d_in, const int* in_sizes, int n_in,
                              void* d_out, int out_size, void* d_ws, size_t ws_size,
                              hipStream_t stream) {
    const float* emb = (const float*)d_in[0];
    const float* center = (const float*)d_in[1];
    const float* rmp = (const float*)d_in[2];
    const float* rhp = (const float*)d_in[3];
    const int* labels = (const int*)d_in[4];
    float* out = (float*)d_out;
    const int B = in_sizes[4];
    const int D = in_sizes[1];

    size_t qBytes = (size_t)B * D;  // fp8 copy
    size_t auxBytes = (size_t)B * 4 + (size_t)D * 4 + 256 + (size_t)B * 4;
    bool pre = ws_size >= qBytes + auxBytes;
    size_t Z0 = pre ? qBytes : 0;

    char* ws = (char*)d_ws;
    unsigned char* embQ = (unsigned char*)ws;
    float* sumexp = (float*)(ws + Z0);
    float* s_m = (float*)(ws + Z0 + (size_t)B * 4);
    float* scal = (float*)(ws + Z0 + (size_t)B * 4 + (size_t)D * 4);
    int* cnt = (int*)(scal + 8);
    float* Sp = (float*)(ws + Z0 + (size_t)B * 4 + (size_t)D * 4 + 256);

    hipMemsetAsync(ws + Z0, 0, (size_t)B * 4 + (size_t)D * 4 + 256, stream);

    k_prep<<<B, D / 4, 0, stream>>>(emb, center, labels, pre ? embQ : nullptr, out, Sp, cnt, D);
    k_colsum<<<B / 32, D / 4, 0, stream>>>(emb, labels, s_m, D);

    int nT = B / 128;
    int nBlocks = nT * (nT + 1) / 2;
    if (pre) k_sumexp_mx<<<nBlocks, 256, 0, stream>>>(embQ, sumexp, D, nT);
    else     k_sumexp_fb<<<nBlocks, 256, 0, stream>>>(emb, sumexp, D, nT);

    k_finalize<<<B / 32, 256, 0, stream>>>(emb, s_m, Sp, sumexp, labels, out, rmp, rhp, scal, D);
    k_final<<<1, 64, 0, stream>>>(scal, cnt, out);
}

// Round 9
// 200.723 us; speedup vs baseline: 1.7118x; 1.4099x over previous
//
#include <hip/hip_runtime.h>

#define INV_T 14.285714285714286f  // 1/0.07
#define C1 0.055803571428571425f   // INV_T / 256 (undoes the 16x-per-input fp8 scale)

typedef float f32x16 __attribute__((ext_vector_type(16)));
typedef float f32x4 __attribute__((ext_vector_type(4)));
typedef int i32x4v __attribute__((ext_vector_type(4)));
typedef int i32x8 __attribute__((ext_vector_type(8)));

__device__ __forceinline__ unsigned char f2e4m3(float f) {
    unsigned char s = (unsigned char)((__float_as_uint(f) >> 24) & 0x80);
    float a = fabsf(f);
    if (a > 448.f) a = 448.f;
    if (a == 0.f) return s;
    int e = (int)((__float_as_uint(a) >> 23) & 0xFF) - 127;
    if (e < -10) return s;
    if (e < -6) e = -6;
    float scale = __int_as_float((unsigned)(130 - e) << 23);  // 2^(3-e)
    int mi = (int)rintf(a * scale);
    if (mi >= 16) { mi >>= 1; ++e; }
    if (mi < 8) return s | (unsigned char)mi;                  // subnormal (e==-6)
    return s | (unsigned char)(((e + 7) << 3) | (mi - 8));
}

__device__ __forceinline__ void async16(void* l, const void* g) {
    __builtin_amdgcn_global_load_lds(
        (const __attribute__((address_space(1))) unsigned int*)g,
        (__attribute__((address_space(3))) unsigned int*)l, 16, 0, 0);
}

// ---- wave-per-row: fp32->fp8(x16) convert + distance + Sp. No LDS/atomics. ----
__global__ void __launch_bounds__(256) k_prep(const float* __restrict__ emb,
                                              const float* __restrict__ center,
                                              unsigned char* __restrict__ embQ,
                                              float* __restrict__ out,
                                              float* __restrict__ Sp, int D, int B) {
    int tid = threadIdx.x;
    int wave = tid >> 6, lane = tid & 63;
    int gw = blockIdx.x * 4 + wave;
    int nw = gridDim.x * 4;
    const float4* c4 = (const float4*)center;
    for (int i = gw; i < B; i += nw) {
        const float4* row = (const float4*)(emb + (size_t)i * D);
        uchar4* qrow = embQ ? (uchar4*)(embQ + (size_t)i * D) : nullptr;
        float d2 = 0.f, sp = 0.f;
#pragma unroll
        for (int j = 0; j < 4; ++j) {
            int idx = lane + j * 64;          // lane-contiguous: 16 segments/instr
            float4 e = row[idx];
            float4 c = c4[idx];
            float dx = e.x - c.x, dy = e.y - c.y, dz = e.z - c.z, dw = e.w - c.w;
            d2 += dx * dx + dy * dy + dz * dz + dw * dw;
            sp += e.x * c.x + e.y * c.y + e.z * c.z + e.w * c.w;
            if (qrow)
                qrow[idx] = make_uchar4(f2e4m3(e.x * 16.f), f2e4m3(e.y * 16.f),
                                        f2e4m3(e.z * 16.f), f2e4m3(e.w * 16.f));
        }
#pragma unroll
        for (int m = 1; m <= 32; m <<= 1) {
            d2 += __shfl_xor(d2, m, 64);
            sp += __shfl_xor(sp, m, 64);
        }
        if (lane == 0) {
            out[5 + i] = sqrtf(d2);
            Sp[i] = sp * INV_T;
        }
    }
}

// ---- s_m[d] = sum over machine rows of emb[:,d]; also counts machines ----
__global__ void __launch_bounds__(256) k_colsum(const float* __restrict__ emb,
                                                const int* __restrict__ labels,
                                                float* __restrict__ s_m,
                                                int* __restrict__ cnt, int D) {
    int t = threadIdx.x;
    int r0 = blockIdx.x * 32;
    float4 acc = {0.f, 0.f, 0.f, 0.f};
#pragma unroll 4
    for (int r = 0; r < 32; ++r) {
        float sc = (labels[r0 + r] == 0) ? 1.f : 0.f;
        float4 v = ((const float4*)(emb + (size_t)(r0 + r) * D))[t];
        acc.x += v.x * sc; acc.y += v.y * sc; acc.z += v.z * sc; acc.w += v.w * sc;
    }
    atomicAdd(&s_m[t * 4 + 0], acc.x);
    atomicAdd(&s_m[t * 4 + 1], acc.y);
    atomicAdd(&s_m[t * 4 + 2], acc.z);
    atomicAdd(&s_m[t * 4 + 3], acc.w);
    if (t == 0) {
        int c = 0;
        for (int r = 0; r < 32; ++r) c += (labels[r0 + r] == 0) ? 1 : 0;
        atomicAdd(cnt, c);   // 256 atomics total (vs 8192 in old k_prep)
    }
}

// ---- sumexp via MX fp8 MFMA; 16-segment DMA staging (R8, unchanged) ----
#define MXMFMA(a, b, c) __builtin_amdgcn_mfma_scale_f32_32x32x64_f8f6f4( \
    (a), (b), (c), 0, 0, 0, 0x7F7F7F7F, 0, 0x7F7F7F7F)

__global__ void __launch_bounds__(256, 2)
k_sumexp_mx(const unsigned char* __restrict__ embQ, float* __restrict__ sumexp,
            int D, int nT) {
    int bid = blockIdx.x;
    const int n = nT;
    float nf = (float)n + 0.5f;
    int rb = (int)(nf - sqrtf(fmaxf(nf * nf - 2.0f * (float)bid, 0.f)));
    if (rb < 0) rb = 0;
    if (rb > n - 1) rb = n - 1;
#define TRI_OFF(r) ((r) * n - ((r) * ((r)-1)) / 2)
    while (rb + 1 <= n - 1 && TRI_OFF(rb + 1) <= bid) ++rb;
    while (rb > 0 && TRI_OFF(rb) > bid) --rb;
    int cb = rb + (bid - TRI_OFF(rb));
#undef TRI_OFF
    int rowbase = rb * 128, colbase = cb * 128;

    int tid = threadIdx.x;
    int wave = tid >> 6, lane = tid & 63;
    int wr = wave >> 1, wc = wave & 1;
    int l31 = lane & 31, kk = lane >> 5;

    __shared__ unsigned char sA[2][16384];
    __shared__ unsigned char sB[2][16384];
    __shared__ float rred[2][128];
    __shared__ float cred[2][128];

    f32x16 acc[2][2];
#pragma unroll
    for (int fr = 0; fr < 2; ++fr)
#pragma unroll
        for (int fc = 0; fc < 2; ++fc)
#pragma unroll
            for (int v = 0; v < 16; ++v) acc[fr][fc][v] = 0.f;

    const int kG = D >> 7;

    const unsigned char* gSA[4];
    const unsigned char* gSB[4];
    unsigned int dstOff[4];
#pragma unroll
    for (int q = 0; q < 4; ++q) {
        int ch = q * 256 + tid;
        int row = ch >> 3, lc = ch & 7;
        int gc = lc ^ (row & 7);
        gSA[q] = embQ + (size_t)(rowbase + row) * D + gc * 16;
        gSB[q] = embQ + (size_t)(colbase + row) * D + gc * 16;
        dstOff[q] = (unsigned)ch << 4;
    }

    auto stage = [&](int buf, int kt) {
        int ko = kt << 7;
#pragma unroll
        for (int q = 0; q < 4; ++q) {
            async16(&sA[buf][dstOff[q]], gSA[q] + ko);
            async16(&sB[buf][dstOff[q]], gSB[q] + ko);
        }
    };

    int e7 = (l31 & 7) << 4;
    int offs[2][2];
#pragma unroll
    for (int h = 0; h < 2; ++h)
#pragma unroll
        for (int j = 0; j < 2; ++j)
            offs[h][j] = (((h * 4 + kk * 2 + j) << 4) ^ e7);
    int aBase0 = (wr * 64 + l31) << 7;
    int aBase1 = aBase0 + (32 << 7);
    int bBase0 = (wc * 64 + l31) << 7;
    int bBase1 = bBase0 + (32 << 7);

    stage(0, 0);
    for (int kt = 0; kt < kG; ++kt) {
        int cur = kt & 1;
        __syncthreads();
        if (kt + 1 < kG) stage(cur ^ 1, kt + 1);
        const unsigned char* A = sA[cur];
        const unsigned char* Bp = sB[cur];
#pragma unroll
        for (int h = 0; h < 2; ++h) {
            i32x8 av[2], bv[2];
            {
                i32x4v lo = *(const i32x4v*)&A[aBase0 + offs[h][0]];
                i32x4v hi = *(const i32x4v*)&A[aBase0 + offs[h][1]];
                av[0] = __builtin_shufflevector(lo, hi, 0, 1, 2, 3, 4, 5, 6, 7);
            }
            {
                i32x4v lo = *(const i32x4v*)&A[aBase1 + offs[h][0]];
                i32x4v hi = *(const i32x4v*)&A[aBase1 + offs[h][1]];
                av[1] = __builtin_shufflevector(lo, hi, 0, 1, 2, 3, 4, 5, 6, 7);
            }
            {
                i32x4v lo = *(const i32x4v*)&Bp[bBase0 + offs[h][0]];
                i32x4v hi = *(const i32x4v*)&Bp[bBase0 + offs[h][1]];
                bv[0] = __builtin_shufflevector(lo, hi, 0, 1, 2, 3, 4, 5, 6, 7);
            }
            {
                i32x4v lo = *(const i32x4v*)&Bp[bBase1 + offs[h][0]];
                i32x4v hi = *(const i32x4v*)&Bp[bBase1 + offs[h][1]];
                bv[1] = __builtin_shufflevector(lo, hi, 0, 1, 2, 3, 4, 5, 6, 7);
            }
#pragma unroll
            for (int fr = 0; fr < 2; ++fr)
#pragma unroll
                for (int fc = 0; fc < 2; ++fc)
                    acc[fr][fc] = MXMFMA(av[fr], bv[fc], acc[fr][fc]);
        }
    }

    float rs[2][16];
    float cs[2] = {0.f, 0.f};
#pragma unroll
    for (int fr = 0; fr < 2; ++fr)
#pragma unroll
        for (int v = 0; v < 16; ++v) rs[fr][v] = 0.f;

#pragma unroll
    for (int fr = 0; fr < 2; ++fr)
#pragma unroll
        for (int fc = 0; fc < 2; ++fc) {
            int gcol = colbase + wc * 64 + fc * 32 + l31;
#pragma unroll
            for (int v = 0; v < 16; ++v) {
                int grow = rowbase + wr * 64 + fr * 32 + (v & 3) + 8 * (v >> 2) + 4 * kk;
                float e = (grow < gcol) ? __expf(acc[fr][fc][v] * C1 - INV_T) : 0.f;
                rs[fr][v] += e;
                cs[fc] += e;
            }
        }

#pragma unroll
    for (int m = 1; m <= 16; m <<= 1)
#pragma unroll
        for (int fr = 0; fr < 2; ++fr)
#pragma unroll
            for (int v = 0; v < 16; ++v) rs[fr][v] += __shfl_xor(rs[fr][v], m, 64);
    if (l31 == 0)
#pragma unroll
        for (int fr = 0; fr < 2; ++fr)
#pragma unroll
            for (int v = 0; v < 16; ++v)
                rred[wc][wr * 64 + fr * 32 + (v & 3) + 8 * (v >> 2) + 4 * kk] = rs[fr][v];

#pragma unroll
    for (int fc = 0; fc < 2; ++fc) cs[fc] += __shfl_xor(cs[fc], 32, 64);
    if (kk == 0)
#pragma unroll
        for (int fc = 0; fc < 2; ++fc) cred[wr][wc * 64 + fc * 32 + l31] = cs[fc];

    __syncthreads();
    if (tid < 128) {
        atomicAdd(&sumexp[rowbase + tid], rred[0][tid] + rred[1][tid]);
    } else {
        int u = tid - 128;
        atomicAdd(&sumexp[colbase + u], cred[0][u] + cred[1][u]);
    }
}

// ---- fallback (no workspace): bf16-via-LDS, fp32 inline convert ----
typedef __bf16 bf16x8 __attribute__((ext_vector_type(8)));
typedef unsigned short u16x8 __attribute__((ext_vector_type(8)));
__device__ __forceinline__ unsigned short f2bf(float f) {
    unsigned int x = __float_as_uint(f);
    x += 0x7fffu + ((x >> 16) & 1u);
    return (unsigned short)(x >> 16);
}
__global__ void __launch_bounds__(256) k_sumexp_fb(const float* __restrict__ embF,
                                                   float* __restrict__ sumexp, int D, int nTiles) {
    int bid = blockIdx.x;
    const int n = nTiles;
    float nf = (float)n + 0.5f;
    int rb = (int)(nf - sqrtf(fmaxf(nf * nf - 2.0f * (float)bid, 0.f)));
    if (rb < 0) rb = 0;
    if (rb > n - 1) rb = n - 1;
#define TRI_OFF(r) ((r) * n - ((r) * ((r)-1)) / 2)
    while (rb + 1 <= n - 1 && TRI_OFF(rb + 1) <= bid) ++rb;
    while (rb > 0 && TRI_OFF(rb) > bid) --rb;
    int cb = rb + (bid - TRI_OFF(rb));
#undef TRI_OFF
    int tid = threadIdx.x;
    int wave = tid >> 6, lane = tid & 63;
    int wr = wave >> 1, wc = wave & 1;
    int quad = lane >> 4, l15 = lane & 15;
    int rowbase = rb * 128, colbase = cb * 128;
    __shared__ unsigned short lA[128 * 64];
    __shared__ unsigned short lB[128 * 64];
    __shared__ float rred[2][128];
    __shared__ float cred[2][128];
    f32x4 zero = {0.f, 0.f, 0.f, 0.f};
    f32x4 acc[4][4];
#pragma unroll
    for (int r = 0; r < 4; ++r)
#pragma unroll
        for (int c = 0; c < 4; ++c) acc[r][c] = zero;
    const int kIters = D >> 6;
    for (int kt = 0; kt < kIters; ++kt) {
        int k0 = kt << 6;
#pragma unroll
        for (int q = 0; q < 4; ++q) {
            int ch = q * 256 + tid;
            int row = ch >> 3, lc = ch & 7;
            int pc = lc ^ (row & 7);
            const float4* sa = (const float4*)(embF + (size_t)(rowbase + row) * D + k0 + lc * 8);
            const float4* sb = (const float4*)(embF + (size_t)(colbase + row) * D + k0 + lc * 8);
            float4 a0 = sa[0], a1 = sa[1];
            float4 b0 = sb[0], b1 = sb[1];
            u16x8 va = {f2bf(a0.x), f2bf(a0.y), f2bf(a0.z), f2bf(a0.w),
                        f2bf(a1.x), f2bf(a1.y), f2bf(a1.z), f2bf(a1.w)};
            u16x8 vb = {f2bf(b0.x), f2bf(b0.y), f2bf(b0.z), f2bf(b0.w),
                        f2bf(b1.x), f2bf(b1.y), f2bf(b1.z), f2bf(b1.w)};
            *(u16x8*)&lA[(row << 6) + (pc << 3)] = va;
            *(u16x8*)&lB[(row << 6) + (pc << 3)] = vb;
        }
        __syncthreads();
#pragma unroll
        for (int h = 0; h < 2; ++h) {
            bf16x8 af[4], bfr[4];
#pragma unroll
            for (int r = 0; r < 4; ++r) {
                int row = wr * 64 + r * 16 + l15;
                int pc = (h * 4 + quad) ^ (l15 & 7);
                af[r] = *(const bf16x8*)&lA[(row << 6) + (pc << 3)];
            }
#pragma unroll
            for (int c = 0; c < 4; ++c) {
                int row = wc * 64 + c * 16 + l15;
                int pc = (h * 4 + quad) ^ (l15 & 7);
                bfr[c] = *(const bf16x8*)&lB[(row << 6) + (pc << 3)];
            }
#pragma unroll
            for (int r = 0; r < 4; ++r)
#pragma unroll
                for (int c = 0; c < 4; ++c)
                    acc[r][c] = __builtin_amdgcn_mfma_f32_16x16x32_bf16(af[r], bfr[c], acc[r][c], 0, 0, 0);
        }
        __syncthreads();
    }
    float rs[4][4], cs[4];
#pragma unroll
    for (int r = 0; r < 4; ++r)
#pragma unroll
        for (int v = 0; v < 4; ++v) rs[r][v] = 0.f;
#pragma unroll
    for (int c = 0; c < 4; ++c) cs[c] = 0.f;
#pragma unroll
    for (int r = 0; r < 4; ++r)
#pragma unroll
        for (int c = 0; c < 4; ++c) {
            f32x4 a = acc[r][c];
            int gcol = colbase + wc * 64 + c * 16 + l15;
#pragma unroll
            for (int v = 0; v < 4; ++v) {
                int grow = rowbase + wr * 64 + r * 16 + quad * 4 + v;
                float e = (grow < gcol) ? __expf((a[v] - 1.0f) * INV_T) : 0.f;
                rs[r][v] += e;
                cs[c] += e;
            }
        }
#pragma unroll
    for (int m = 1; m <= 8; m <<= 1)
#pragma unroll
        for (int r = 0; r < 4; ++r)
#pragma unroll
            for (int v = 0; v < 4; ++v) rs[r][v] += __shfl_xor(rs[r][v], m, 64);
    if (l15 == 0)
#pragma unroll
        for (int r = 0; r < 4; ++r)
#pragma unroll
            for (int v = 0; v < 4; ++v)
                rred[wc][wr * 64 + r * 16 + quad * 4 + v] = rs[r][v];
#pragma unroll
    for (int m = 16; m <= 32; m <<= 1)
#pragma unroll
        for (int c = 0; c < 4; ++c) cs[c] += __shfl_xor(cs[c], m, 64);
    if (quad == 0)
#pragma unroll
        for (int c = 0; c < 4; ++c) cred[wr][wc * 64 + c * 16 + l15] = cs[c];
    __syncthreads();
    if (tid < 128) {
        atomicAdd(&sumexp[rowbase + tid], rred[0][tid] + rred[1][tid]);
    } else {
        int u = tid & 127;
        atomicAdd(&sumexp[colbase + u], cred[0][u] + cred[1][u]);
    }
}

// ---- per-row finalize (lane-contiguous loads) ----
__global__ void __launch_bounds__(256) k_finalize(const float* __restrict__ emb,
                                                  const float* __restrict__ s_m,
                                                  const float* __restrict__ Sp,
                                                  const float* __restrict__ sumexp,
                                                  const int* __restrict__ labels,
                                                  const float* __restrict__ outv,
                                                  const float* __restrict__ rmp,
                                                  const float* __restrict__ rhp,
                                                  float* __restrict__ scal, int D) {
    int tid = threadIdx.x;
    int wave = tid >> 6, lane = tid & 63;
    __shared__ float ac[8];
    if (tid < 8) ac[tid] = 0.f;
    __syncthreads();
    float rm = rmp[0], rh = rhp[0];
    const float4* sm4 = (const float4*)s_m;
    for (int it = 0; it < 8; ++it) {
        int i = blockIdx.x * 32 + it * 4 + wave;
        const float4* row = (const float4*)(emb + (size_t)i * D);
        float q = 0.f, sd = 0.f;
#pragma unroll
        for (int j = 0; j < 4; ++j) {
            int idx = lane + j * 64;          // lane-contiguous: 16 segments/instr
            float4 e = row[idx];
            float4 s = sm4[idx];
            q += e.x * s.x + e.y * s.y + e.z * s.z + e.w * s.w;
            sd += e.x * e.x + e.y * e.y + e.z * e.z + e.w * e.w;
        }
#pragma unroll
        for (int m = 1; m <= 32; m <<= 1) {
            q += __shfl_xor(q, m, 64);
            sd += __shfl_xor(sd, m, 64);
        }
        if (lane == 0) {
            float LP = Sp[i];
            float eS = __expf(LP - INV_T);
            float lse = INV_T + __logf(sumexp[i] + eS);
            bool mach = (labels[i] == 0);
            float pos = (q - (mach ? sd : 0.f)) * INV_T + LP;
            float d = outv[5 + i];
            atomicAdd(&ac[2], eS);
            if (mach) {
                atomicAdd(&ac[4], lse);
                atomicAdd(&ac[5], pos);
                atomicAdd(&ac[3], LP);
                float x = d - rm;
                if (x > 0.f) atomicAdd(&ac[0], x * x);
            } else {
                float x = rh - d;
                if (x > 0.f) atomicAdd(&ac[1], x * x);
            }
        }
    }
    __syncthreads();
    if (tid < 8) atomicAdd(&scal[tid], ac[tid]);
}

// ---- combine scalars ----
__global__ void k_final(const float* __restrict__ scal, const int* __restrict__ cnt,
                        float* __restrict__ out, int B) {
    if (threadIdx.x == 0) {
        int nm = cnt[0], nh = B - nm;
        float nmf = (float)(nm > 1 ? nm : 1);
        float nhf = (float)(nh > 1 ? nh : 1);
        float loss_m = scal[0] / nmf;
        float loss_h = scal[1] / nhf;
        float loss_shell = loss_m + loss_h;
        float lse_p = INV_T + __logf(scal[2]);
        float proto = lse_p - scal[3] / nmf;
        float con = scal[4] - scal[5] / nmf;
        int denom = (nm + 1 > 1) ? nm + 1 : 1;
        float lc = (con + proto) / (float)denom;
        if (!(nm > 0 && nh > 0)) lc = 0.f;
        out[0] = loss_shell + lc;
        out[1] = loss_shell;
        out[2] = loss_m;
        out[3] = loss_h;
        out[4] = lc;
    }
}

extern "C" void kernel_launch(void* const* d_in, const int* in_sizes, int n_in,
                              void* d_out, int out_size, void* d_ws, size_t ws_size,
                              hipStream_t stream) {
    const float* emb = (const float*)d_in[0];
    const float* center = (const float*)d_in[1];
    const float* rmp = (const float*)d_in[2];
    const float* rhp = (const float*)d_in[3];
    const int* labels = (const int*)d_in[4];
    float* out = (float*)d_out;
    const int B = in_sizes[4];
    const int D = in_sizes[1];

    size_t qBytes = (size_t)B * D;  // fp8 copy
    size_t auxBytes = (size_t)B * 4 + (size_t)D * 4 + 256 + (size_t)B * 4;
    bool pre = ws_size >= qBytes + auxBytes;
    size_t Z0 = pre ? qBytes : 0;

    char* ws = (char*)d_ws;
    unsigned char* embQ = (unsigned char*)ws;
    float* sumexp = (float*)(ws + Z0);
    float* s_m = (float*)(ws + Z0 + (size_t)B * 4);
    float* scal = (float*)(ws + Z0 + (size_t)B * 4 + (size_t)D * 4);
    int* cnt = (int*)(scal + 8);
    float* Sp = (float*)(ws + Z0 + (size_t)B * 4 + (size_t)D * 4 + 256);

    hipMemsetAsync(ws + Z0, 0, (size_t)B * 4 + (size_t)D * 4 + 256, stream);

    k_prep<<<512, 256, 0, stream>>>(emb, center, pre ? embQ : nullptr, out, Sp, D, B);
    k_colsum<<<B / 32, D / 4, 0, stream>>>(emb, labels, s_m, cnt, D);

    int nT = B / 128;
    int nBlocks = nT * (nT + 1) / 2;
    if (pre) k_sumexp_mx<<<nBlocks, 256, 0, stream>>>(embQ, sumexp, D, nT);
    else     k_sumexp_fb<<<nBlocks, 256, 0, stream>>>(emb, sumexp, D, nT);

    k_finalize<<<B / 32, 256, 0, stream>>>(emb, s_m, Sp, sumexp, labels, out, rmp, rhp, scal, D);
    k_final<<<1, 64, 0, stream>>>(scal, cnt, out, B);
}